// Round 4
// baseline (3975.529 us; speedup 1.0000x reference)
//
#include <hip/hip_runtime.h>
#include <math.h>

#define EMBED 128

// ---------------------------------------------------------------------------
// pairs dtype detector: reference declares int64 but harness may hand int32.
// int64 little-endian: every odd 32-bit slot is a high word of a value
// < 100000 -> zero. int32: odd slots are random t indices.
// ---------------------------------------------------------------------------
__global__ void detect_kernel(const unsigned int* __restrict__ pairs,
                              int* __restrict__ flag) {
    unsigned v = 0;
    int lane = threadIdx.x;  // 64 lanes
#pragma unroll
    for (int i = 0; i < 8; ++i) {
        v |= pairs[2 * (lane * 8 + i) + 1];
    }
    unsigned long long b = __ballot(v != 0);
    if (lane == 0) *flag = (b != 0ULL) ? 1 : 0;
}

// ---------------------------------------------------------------------------
// Node precompute v2: thread -> (p, jt). p in [0, 2*n_nodes) is the table
// row (node*2 + which), jt in [0,4) selects a 32-col tile. acc[32] keeps
// VGPR small (occupancy fix vs round-3's acc[128] AGPR disaster).
// jt in the LOW bits -> 4 consecutive lanes cover one row's 128 cols
// -> coalesced weight reads and table writes.
// which==0: tab row = b1 + h[node] @ W1[0:128]      (A, b1 folded)
// which==1: tab row =      h[node] @ W1[128:256]    (B)
// ---------------------------------------------------------------------------
__global__ __launch_bounds__(256) void node_pre_kernel(
    const float* __restrict__ h, const float* __restrict__ W1,
    const float* __restrict__ b1, float* __restrict__ tab, int n2)
{
    int t = blockIdx.x * 256 + threadIdx.x;
    if (t >= n2 * 4) return;
    int jt = t & 3;          // 32-col tile
    int p  = t >> 2;         // table row
    int node  = p >> 1;
    int which = p & 1;

    const float4* __restrict__ hv = (const float4*)(h + (size_t)node * EMBED);
    const float* __restrict__ W = W1 + (size_t)which * 128 * 128 + jt * 32;

    float acc[32];
    if (which == 0) {
#pragma unroll
        for (int j = 0; j < 32; ++j) acc[j] = b1[jt * 32 + j];
    } else {
#pragma unroll
        for (int j = 0; j < 32; ++j) acc[j] = 0.0f;
    }

#pragma unroll 1
    for (int d4 = 0; d4 < EMBED / 4; ++d4) {
        float4 a = hv[d4];
        float av[4] = {a.x, a.y, a.z, a.w};
#pragma unroll
        for (int dd = 0; dd < 4; ++dd) {
            float f = av[dd];
            const float4* __restrict__ w4 =
                (const float4*)(W + (size_t)(d4 * 4 + dd) * 128);
#pragma unroll
            for (int j4 = 0; j4 < 8; ++j4) {
                float4 w = w4[j4];
                acc[4 * j4 + 0] = fmaf(f, w.x, acc[4 * j4 + 0]);
                acc[4 * j4 + 1] = fmaf(f, w.y, acc[4 * j4 + 1]);
                acc[4 * j4 + 2] = fmaf(f, w.z, acc[4 * j4 + 2]);
                acc[4 * j4 + 3] = fmaf(f, w.w, acc[4 * j4 + 3]);
            }
        }
    }

    float4* __restrict__ o = (float4*)(tab + (size_t)p * 128 + jt * 32);
#pragma unroll
    for (int j4 = 0; j4 < 8; ++j4)
        o[j4] = make_float4(acc[4 * j4], acc[4 * j4 + 1],
                            acc[4 * j4 + 2], acc[4 * j4 + 3]);
}

// ---------------------------------------------------------------------------
// Cooperative pair kernel: 256-thread block handles 64 pairs.
// Phase A: lane (tid&63) = pair, wave (tid>>6) = 32-wide j-tile of layer 1.
//   acc = A[s]+B[t] slice, += (hs*ht)@W1c + |hs-ht|@W1d slice. acc[32] only.
//   Weight addresses are wave-uniform (broadcast); hs/ht are lane gathers.
// x1 -> LDS, stride 132 floats (33 float4 granules, coprime 32 -> no bank
// conflicts on write or read).
// Phase B: lane = pair, wave = 16-wide layer-2 j-tile; layer-3 partials
// reduced through a tiny LDS buffer.
// ---------------------------------------------------------------------------
__global__ __launch_bounds__(256) void pair_kernel_f(
    const float* __restrict__ h,
    const int* __restrict__ pairs,
    const int* __restrict__ flag,
    const float* __restrict__ tab,
    const float* __restrict__ W1,
    const float* __restrict__ W2, const float* __restrict__ b2,
    const float* __restrict__ W3, const float* __restrict__ b3,
    float* __restrict__ out, int npairs)
{
    __shared__ float x1s[64 * 132];      // 33.8 KB, padded stride
    __shared__ float4 part4[64];         // layer-3 partials

    int lane = threadIdx.x & 63;         // pair within block
    int wv   = threadIdx.x >> 6;         // 0..3
    int pbase = blockIdx.x * 64;
    int p  = pbase + lane;
    int pc = p < npairs ? p : npairs - 1;   // clamp tail (no OOB gathers)

    int s, t;
    if (*flag == 0) {   // int64 layout: low words at 4p, 4p+2
        s = pairs[4 * pc];
        t = pairs[4 * pc + 2];
    } else {            // int32 layout
        s = pairs[2 * pc];
        t = pairs[2 * pc + 1];
    }

    // ---- phase A: layer-1 slice j in [wv*32, wv*32+32) ----
    const float4* __restrict__ As =
        (const float4*)(tab + (size_t)(2 * s) * 128 + wv * 32);
    const float4* __restrict__ Bt =
        (const float4*)(tab + (size_t)(2 * t + 1) * 128 + wv * 32);

    float acc[32];
#pragma unroll
    for (int j4 = 0; j4 < 8; ++j4) {
        float4 a = As[j4];
        float4 b = Bt[j4];
        acc[4 * j4 + 0] = a.x + b.x;
        acc[4 * j4 + 1] = a.y + b.y;
        acc[4 * j4 + 2] = a.z + b.z;
        acc[4 * j4 + 3] = a.w + b.w;
    }

    const float4* __restrict__ hs4 = (const float4*)(h + (size_t)s * EMBED);
    const float4* __restrict__ ht4 = (const float4*)(h + (size_t)t * EMBED);
    const float* __restrict__ Wc = W1 + (size_t)256 * 128 + wv * 32;
    const float* __restrict__ Wd = W1 + (size_t)384 * 128 + wv * 32;

#pragma unroll 1
    for (int d4 = 0; d4 < EMBED / 4; ++d4) {
        float4 a = hs4[d4];
        float4 b = ht4[d4];
        float av[4] = {a.x, a.y, a.z, a.w};
        float bv[4] = {b.x, b.y, b.z, b.w};
#pragma unroll
        for (int dd = 0; dd < 4; ++dd) {
            int d = d4 * 4 + dd;
            float f2 = av[dd] * bv[dd];
            float f3 = fabsf(av[dd] - bv[dd]);
            const float4* __restrict__ wc4 = (const float4*)(Wc + (size_t)d * 128);
            const float4* __restrict__ wd4 = (const float4*)(Wd + (size_t)d * 128);
#pragma unroll
            for (int j4 = 0; j4 < 8; ++j4) {
                float4 wc = wc4[j4];
                float4 wd = wd4[j4];
                float v0 = acc[4 * j4 + 0], v1 = acc[4 * j4 + 1];
                float v2 = acc[4 * j4 + 2], v3 = acc[4 * j4 + 3];
                v0 = fmaf(f2, wc.x, v0); v0 = fmaf(f3, wd.x, v0);
                v1 = fmaf(f2, wc.y, v1); v1 = fmaf(f3, wd.y, v1);
                v2 = fmaf(f2, wc.z, v2); v2 = fmaf(f3, wd.z, v2);
                v3 = fmaf(f2, wc.w, v3); v3 = fmaf(f3, wd.w, v3);
                acc[4 * j4 + 0] = v0; acc[4 * j4 + 1] = v1;
                acc[4 * j4 + 2] = v2; acc[4 * j4 + 3] = v3;
            }
        }
    }

    // relu + store x1 slice to LDS (granule index 33*lane + c: conflict-free)
    {
        float4* __restrict__ x1w = (float4*)x1s;
#pragma unroll
        for (int j4 = 0; j4 < 8; ++j4) {
            x1w[lane * 33 + wv * 8 + j4] =
                make_float4(fmaxf(acc[4 * j4 + 0], 0.0f),
                            fmaxf(acc[4 * j4 + 1], 0.0f),
                            fmaxf(acc[4 * j4 + 2], 0.0f),
                            fmaxf(acc[4 * j4 + 3], 0.0f));
        }
    }
    __syncthreads();

    // ---- phase B: layer 2 slice j in [wv*16, wv*16+16) ----
    float acc2[16];
#pragma unroll
    for (int i = 0; i < 16; ++i) acc2[i] = b2[wv * 16 + i];

    const float4* __restrict__ x1r = (const float4*)x1s;
#pragma unroll 1
    for (int k4 = 0; k4 < 32; ++k4) {
        float4 xv = x1r[lane * 33 + k4];
        float xa[4] = {xv.x, xv.y, xv.z, xv.w};
#pragma unroll
        for (int kk = 0; kk < 4; ++kk) {
            int k = 4 * k4 + kk;
            float x = xa[kk];
            const float4* __restrict__ w2 =
                (const float4*)(W2 + (size_t)k * 64 + wv * 16);
#pragma unroll
            for (int i4 = 0; i4 < 4; ++i4) {
                float4 w = w2[i4];
                acc2[4 * i4 + 0] = fmaf(x, w.x, acc2[4 * i4 + 0]);
                acc2[4 * i4 + 1] = fmaf(x, w.y, acc2[4 * i4 + 1]);
                acc2[4 * i4 + 2] = fmaf(x, w.z, acc2[4 * i4 + 2]);
                acc2[4 * i4 + 3] = fmaf(x, w.w, acc2[4 * i4 + 3]);
            }
        }
    }

    // ---- layer 3 partial over this thread's 16 outputs ----
    float pp = 0.0f;
#pragma unroll
    for (int i = 0; i < 16; ++i)
        pp = fmaf(fmaxf(acc2[i], 0.0f), W3[wv * 16 + i], pp);

    ((float*)&part4[lane])[wv] = pp;
    __syncthreads();

    if (threadIdx.x < 64) {
        int po = pbase + threadIdx.x;
        if (po < npairs) {
            float4 q = part4[threadIdx.x];
            out[po] = q.x + q.y + q.z + q.w + b3[0];
        }
    }
}

// ---------------------------------------------------------------------------
// Fallback: direct per-pair kernel (only if d_ws can't hold the node tables).
// ---------------------------------------------------------------------------
__global__ __launch_bounds__(256) void mlp_kernel(
    const float* __restrict__ h,
    const int* __restrict__ pairs,
    const int* __restrict__ flag,
    const float* __restrict__ W1, const float* __restrict__ b1,
    const float* __restrict__ W2, const float* __restrict__ b2,
    const float* __restrict__ W3, const float* __restrict__ b3,
    float* __restrict__ out, int npairs)
{
    int p = blockIdx.x * 256 + threadIdx.x;
    if (p >= npairs) return;

    int s, t;
    if (*flag == 0) {
        s = pairs[4 * p];
        t = pairs[4 * p + 2];
    } else {
        s = pairs[2 * p];
        t = pairs[2 * p + 1];
    }

    const float4* __restrict__ hs4 = (const float4*)(h + (size_t)s * EMBED);
    const float4* __restrict__ ht4 = (const float4*)(h + (size_t)t * EMBED);

    float acc[128];
#pragma unroll
    for (int j = 0; j < 128; ++j) acc[j] = b1[j];

#pragma unroll 1
    for (int d4 = 0; d4 < EMBED / 4; ++d4) {
        float4 a = hs4[d4];
        float4 b = ht4[d4];
        float av[4] = {a.x, a.y, a.z, a.w};
        float bv[4] = {b.x, b.y, b.z, b.w};
#pragma unroll
        for (int dd = 0; dd < 4; ++dd) {
            int k = d4 * 4 + dd;
            float f0 = av[dd];
            float f1 = bv[dd];
            float f2 = f0 * f1;
            float f3 = fabsf(f0 - f1);
            const float* __restrict__ w0 = W1 + (size_t)k * 128;
            const float* __restrict__ w1r = w0 + 128 * 128;
            const float* __restrict__ w2r = w0 + 256 * 128;
            const float* __restrict__ w3r = w0 + 384 * 128;
#pragma unroll
            for (int j = 0; j < 128; ++j) {
                float v0 = acc[j];
                v0 = fmaf(f0, w0[j], v0);
                v0 = fmaf(f1, w1r[j], v0);
                v0 = fmaf(f2, w2r[j], v0);
                v0 = fmaf(f3, w3r[j], v0);
                acc[j] = v0;
            }
        }
    }

#pragma unroll
    for (int j = 0; j < 128; ++j) acc[j] = fmaxf(acc[j], 0.0f);

    float x2[64];
#pragma unroll
    for (int j = 0; j < 64; ++j) x2[j] = b2[j];
#pragma unroll
    for (int k = 0; k < 128; ++k) {
        float xv = acc[k];
#pragma unroll
        for (int j = 0; j < 64; ++j)
            x2[j] = fmaf(xv, W2[(size_t)k * 64 + j], x2[j]);
    }

    float lg = b3[0];
#pragma unroll
    for (int k = 0; k < 64; ++k)
        lg = fmaf(fmaxf(x2[k], 0.0f), W3[k], lg);

    out[p] = lg;
}

extern "C" void kernel_launch(void* const* d_in, const int* in_sizes, int n_in,
                              void* d_out, int out_size, void* d_ws, size_t ws_size,
                              hipStream_t stream) {
    const float* h   = (const float*)d_in[0];
    const int* pairs = (const int*)d_in[1];
    const float* W1  = (const float*)d_in[2];
    const float* b1  = (const float*)d_in[3];
    const float* W2  = (const float*)d_in[4];
    const float* b2  = (const float*)d_in[5];
    const float* W3  = (const float*)d_in[6];
    const float* b3  = (const float*)d_in[7];
    float* out = (float*)d_out;

    int npairs  = out_size;               // one logit per pair
    int n_nodes = in_sizes[0] / EMBED;

    int*   flag = (int*)d_ws;
    float* tab  = (float*)((char*)d_ws + 16);   // keep 16B alignment
    size_t need = 16 + (size_t)n_nodes * 2 * EMBED * sizeof(float);

    detect_kernel<<<1, 64, 0, stream>>>((const unsigned int*)pairs, flag);

    if (ws_size >= need) {
        int n2 = 2 * n_nodes;
        int nthreads = n2 * 4;            // 4 col-tiles per table row
        node_pre_kernel<<<(nthreads + 255) / 256, 256, 0, stream>>>(
            h, W1, b1, tab, n2);
        pair_kernel_f<<<(npairs + 63) / 64, 256, 0, stream>>>(
            h, pairs, flag, tab, W1, W2, b2, W3, b3, out, npairs);
    } else {
        mlp_kernel<<<(npairs + 255) / 256, 256, 0, stream>>>(
            h, pairs, flag, W1, b1, W2, b2, W3, b3, out, npairs);
    }
}

// Round 5
// 702.750 us; speedup vs baseline: 5.6571x; 5.6571x over previous
//
#include <hip/hip_runtime.h>
#include <math.h>

#define EMBED 128

// ---------------------------------------------------------------------------
// pairs dtype detector: reference declares int64 but harness may hand int32.
// int64 LE: odd 32-bit slots are high words of values < 100000 -> zero.
// ---------------------------------------------------------------------------
__global__ void detect_kernel(const unsigned int* __restrict__ pairs,
                              int* __restrict__ flag) {
    unsigned v = 0;
    int lane = threadIdx.x;  // 64 lanes
#pragma unroll
    for (int i = 0; i < 8; ++i) {
        v |= pairs[2 * (lane * 8 + i) + 1];
    }
    unsigned long long b = __ballot(v != 0);
    if (lane == 0) *flag = (b != 0ULL) ? 1 : 0;
}

// ---------------------------------------------------------------------------
// Node precompute v3 (GEMM-tiled): block = 64 nodes x 256 cols.
// cols 0..127 -> A table (b1 + h@W1a), cols 128..255 -> B table (h@W1b).
// W1ab staged per 16-dim chunk in LDS [16][260-pad]; h-tile transposed to
// LDS [16 dims][64 nodes]. Thread = 4 nodes x 16 cols; per k: 1+4 b128
// LDS reads (2-way/bcast = free) feed 64 FMAs. Weight reuse = 64 nodes.
// ---------------------------------------------------------------------------
__global__ __launch_bounds__(256) void node_pre_kernel(
    const float* __restrict__ h, const float* __restrict__ W1,
    const float* __restrict__ b1, float* __restrict__ tab, int n_nodes)
{
    __shared__ float Wab[16 * 260];   // 16.25 KB, stride 260 breaks bank collisions
    __shared__ float Fh[16 * 64];     // 4 KB, [dim][node]

    int tid = threadIdx.x;
    int pg  = tid & 15;               // node group: 4 nodes
    int cg  = tid >> 4;               // col group: 16 of 256 cols
    int nb  = blockIdx.x * 64;

    const float4* hP = nullptr;
    if (tid < 64) {
        int n = nb + tid; if (n >= n_nodes) n = n_nodes - 1;
        hP = (const float4*)(h + (size_t)n * EMBED);
    }

    float acc[4][16];
#pragma unroll
    for (int a = 0; a < 4; ++a)
#pragma unroll
        for (int b = 0; b < 16; ++b) acc[a][b] = 0.0f;

    int wr   = tid >> 4;              // 0..15: Wab row (dim within chunk)
    int wseg = tid & 15;              // 16-float segment of 256 cols

#pragma unroll 1
    for (int c = 0; c < 8; ++c) {
        // ---- stage Wab chunk: rows = dims c*16..c*16+15, cols 0..255 ----
        {
            const float* src = (wseg < 8)
                ? (W1 + (size_t)(c * 16 + wr) * 128 + wseg * 16)
                : (W1 + (size_t)(128 + c * 16 + wr) * 128 + (wseg - 8) * 16);
            float* dst = Wab + wr * 260 + ((wseg < 8) ? wseg * 16
                                                      : 128 + (wseg - 8) * 16);
            const float4* s4 = (const float4*)src;
            float4* d4 = (float4*)dst;
#pragma unroll
            for (int q = 0; q < 4; ++q) d4[q] = s4[q];
        }
        // ---- stage h-tile transposed ----
        if (tid < 64) {
#pragma unroll
            for (int q = 0; q < 4; ++q) {
                float4 v = hP[c * 4 + q];
                Fh[(q * 4 + 0) * 64 + tid] = v.x;
                Fh[(q * 4 + 1) * 64 + tid] = v.y;
                Fh[(q * 4 + 2) * 64 + tid] = v.z;
                Fh[(q * 4 + 3) * 64 + tid] = v.w;
            }
        }
        __syncthreads();
        // ---- compute 16 k ----
#pragma unroll 4
        for (int k = 0; k < 16; ++k) {
            float4 f = *(const float4*)(Fh + k * 64 + pg * 4);
            float fa[4] = {f.x, f.y, f.z, f.w};
            const float4* wrow = (const float4*)(Wab + k * 260 + cg * 16);
#pragma unroll
            for (int q = 0; q < 4; ++q) {
                float4 w = wrow[q];
                float wa[4] = {w.x, w.y, w.z, w.w};
#pragma unroll
                for (int a = 0; a < 4; ++a)
#pragma unroll
                    for (int b = 0; b < 4; ++b)
                        acc[a][q * 4 + b] = fmaf(fa[a], wa[b], acc[a][q * 4 + b]);
            }
        }
        __syncthreads();
    }

    // ---- epilogue: + b1 (A half only), write tab ----
    float bias[16];
    if (cg < 8) {
        const float4* b4 = (const float4*)(b1 + cg * 16);
#pragma unroll
        for (int q = 0; q < 4; ++q) {
            float4 v = b4[q];
            bias[q * 4 + 0] = v.x; bias[q * 4 + 1] = v.y;
            bias[q * 4 + 2] = v.z; bias[q * 4 + 3] = v.w;
        }
    } else {
#pragma unroll
        for (int b = 0; b < 16; ++b) bias[b] = 0.0f;
    }
#pragma unroll
    for (int a = 0; a < 4; ++a) {
        int n = nb + pg * 4 + a;
        if (n < n_nodes) {
            int row = (cg < 8) ? 2 * n : 2 * n + 1;
            int col = (cg < 8) ? cg * 16 : (cg - 8) * 16;
            float4* dst = (float4*)(tab + (size_t)row * 128 + col);
#pragma unroll
            for (int q = 0; q < 4; ++q)
                dst[q] = make_float4(acc[a][q * 4 + 0] + bias[q * 4 + 0],
                                     acc[a][q * 4 + 1] + bias[q * 4 + 1],
                                     acc[a][q * 4 + 2] + bias[q * 4 + 2],
                                     acc[a][q * 4 + 3] + bias[q * 4 + 3]);
        }
    }
}

// ---------------------------------------------------------------------------
// Pair kernel v3 (GEMM-tiled): block = 64 pairs x 128 j (layer 1).
// k = 256 virtual rows (f2 = hs*ht dims 0..127 -> chunk rows 0..15,
// f3 = |hs-ht| -> rows 16..31 per 16-dim chunk). Per chunk: Wc/Wd rows
// staged to LDS [32][132-pad], F-tile built in LDS [32][68-pad] from
// gathered hs/ht. Thread = 4 pairs x 8 j. Epilogue: + tab gathers
// (A[s]+B[t]), relu, transpose x1 through LDS, layer-2 from LDS-staged
// W2, layer-3 reduced through LDS.
// ---------------------------------------------------------------------------
__global__ __launch_bounds__(256) void pair_kernel_f(
    const float* __restrict__ h,
    const int* __restrict__ pairs,
    const int* __restrict__ flag,
    const float* __restrict__ tab,
    const float* __restrict__ W1,
    const float* __restrict__ W2, const float* __restrict__ b2,
    const float* __restrict__ W3, const float* __restrict__ b3,
    float* __restrict__ out, int npairs)
{
    __shared__ float x1T[128 * 68];     // 34 KB: [j][pair] transpose, stride 68
    __shared__ float reg2[128 * 68];    // 34 KB union: {Fb+Wb} then {W2s}
    __shared__ int sArr[64], tArr[64];

    float* Fb = reg2;                   // [32][68]  = 2176 floats
    float* Wb = reg2 + 32 * 68;         // [32][132] = 4224 floats (6400 < 8704)

    int tid = threadIdx.x;
    int pg  = tid & 15;                 // pair group: 4 pairs
    int jg  = tid >> 4;                 // j group: 8 cols of 128
    int pb  = blockIdx.x * 64;

    if (tid < 64) {
        int p = pb + tid; if (p >= npairs) p = npairs - 1;
        int s, t;
        if (*flag == 0) { s = pairs[4 * p]; t = pairs[4 * p + 2]; }
        else            { s = pairs[2 * p]; t = pairs[2 * p + 1]; }
        sArr[tid] = s; tArr[tid] = t;
    }
    __syncthreads();

    const float4* hsP = nullptr;
    const float4* htP = nullptr;
    int dh = (tid >> 6) & 1;            // dim-half for F-gen (tid<128)
    if (tid < 128) {
        int pr = tid & 63;
        hsP = (const float4*)(h + (size_t)sArr[pr] * EMBED);
        htP = (const float4*)(h + (size_t)tArr[pr] * EMBED);
    }

    float acc[4][8];
#pragma unroll
    for (int a = 0; a < 4; ++a)
#pragma unroll
        for (int b = 0; b < 8; ++b) acc[a][b] = 0.0f;

    int wr   = tid >> 3;                // 0..31: Wb row
    int wseg = tid & 7;                 // 16-float segment of 128 cols
    const float* WcBase = W1 + (size_t)256 * 128;
    const float* WdBase = W1 + (size_t)384 * 128;

#pragma unroll 1
    for (int c = 0; c < 8; ++c) {
        // ---- stage Wb: rows 0..15 = Wc dims, 16..31 = Wd dims ----
        {
            const float* src = (wr < 16)
                ? WcBase + (size_t)(c * 16 + wr) * 128 + wseg * 16
                : WdBase + (size_t)(c * 16 + wr - 16) * 128 + wseg * 16;
            const float4* s4 = (const float4*)src;
            float4* d4 = (float4*)(Wb + wr * 132 + wseg * 16);
#pragma unroll
            for (int q = 0; q < 4; ++q) d4[q] = s4[q];
        }
        // ---- build F-tile: threads 0..127, 8 dims each ----
        if (tid < 128) {
            int pr = tid & 63;
            float4 a0 = hsP[c * 4 + dh * 2 + 0];
            float4 a1 = hsP[c * 4 + dh * 2 + 1];
            float4 b0 = htP[c * 4 + dh * 2 + 0];
            float4 b1v = htP[c * 4 + dh * 2 + 1];
            float av[8] = {a0.x, a0.y, a0.z, a0.w, a1.x, a1.y, a1.z, a1.w};
            float bv[8] = {b0.x, b0.y, b0.z, b0.w, b1v.x, b1v.y, b1v.z, b1v.w};
#pragma unroll
            for (int dd = 0; dd < 8; ++dd) {
                int k2 = dh * 8 + dd;                       // 0..15
                Fb[k2 * 68 + pr]        = av[dd] * bv[dd];  // f2 row
                Fb[(16 + k2) * 68 + pr] = fabsf(av[dd] - bv[dd]); // f3 row
            }
        }
        __syncthreads();
        // ---- compute 32 k ----
#pragma unroll 4
        for (int k = 0; k < 32; ++k) {
            float4 f = *(const float4*)(Fb + k * 68 + pg * 4);
            float fa[4] = {f.x, f.y, f.z, f.w};
            const float4* wrow = (const float4*)(Wb + k * 132 + jg * 8);
            float4 w0 = wrow[0], w1 = wrow[1];
            float wa[8] = {w0.x, w0.y, w0.z, w0.w, w1.x, w1.y, w1.z, w1.w};
#pragma unroll
            for (int a = 0; a < 4; ++a)
#pragma unroll
                for (int b = 0; b < 8; ++b)
                    acc[a][b] = fmaf(fa[a], wa[b], acc[a][b]);
        }
        __syncthreads();
    }

    // ---- stage W2s into reg2 (Fb/Wb dead) ----
    {
        int r = tid >> 1, hf = tid & 1;
        const float4* s4 = (const float4*)(W2 + (size_t)r * 64 + hf * 32);
        float4* d4 = (float4*)(reg2 + r * 68 + hf * 32);
#pragma unroll
        for (int q = 0; q < 8; ++q) d4[q] = s4[q];
    }

    // ---- epilogue L1: + A[s]+B[t], relu, transpose into x1T ----
    {
        float xr[4][8];
#pragma unroll
        for (int a = 0; a < 4; ++a) {
            int s = sArr[pg * 4 + a], t = tArr[pg * 4 + a];
            const float4* A4 = (const float4*)(tab + (size_t)(2 * s) * 128 + jg * 8);
            const float4* B4 = (const float4*)(tab + (size_t)(2 * t + 1) * 128 + jg * 8);
            float4 A0 = A4[0], A1 = A4[1], B0 = B4[0], B1 = B4[1];
            float ab[8] = {A0.x + B0.x, A0.y + B0.y, A0.z + B0.z, A0.w + B0.w,
                           A1.x + B1.x, A1.y + B1.y, A1.z + B1.z, A1.w + B1.w};
#pragma unroll
            for (int b = 0; b < 8; ++b)
                xr[a][b] = fmaxf(acc[a][b] + ab[b], 0.0f);
        }
#pragma unroll
        for (int b = 0; b < 8; ++b) {
            *(float4*)(x1T + (jg * 8 + b) * 68 + pg * 4) =
                make_float4(xr[0][b], xr[1][b], xr[2][b], xr[3][b]);
        }
    }
    __syncthreads();

    // ---- layer 2: x2[64] = b2 + x1 @ W2, thread = 4 pairs x 4 j2 ----
    float acc2[4][4];
#pragma unroll
    for (int b = 0; b < 4; ++b) {
        float bb = b2[jg * 4 + b];
#pragma unroll
        for (int a = 0; a < 4; ++a) acc2[a][b] = bb;
    }
#pragma unroll 4
    for (int k = 0; k < 128; ++k) {
        float4 xv = *(const float4*)(x1T + k * 68 + pg * 4);
        float4 wv = *(const float4*)(reg2 + k * 68 + jg * 4);
        float xa[4] = {xv.x, xv.y, xv.z, xv.w};
        float wa[4] = {wv.x, wv.y, wv.z, wv.w};
#pragma unroll
        for (int a = 0; a < 4; ++a)
#pragma unroll
            for (int b = 0; b < 4; ++b)
                acc2[a][b] = fmaf(xa[a], wa[b], acc2[a][b]);
    }
    __syncthreads();   // x1T reads done before partial overwrite

    // ---- layer 3 partials -> LDS [64 pairs][17] (reuse x1T region) ----
    {
        float4 w3v = *(const float4*)(W3 + jg * 4);
#pragma unroll
        for (int a = 0; a < 4; ++a) {
            float pp = fmaf(fmaxf(acc2[a][0], 0.0f), w3v.x,
                       fmaf(fmaxf(acc2[a][1], 0.0f), w3v.y,
                       fmaf(fmaxf(acc2[a][2], 0.0f), w3v.z,
                            fmaxf(acc2[a][3], 0.0f) * w3v.w)));
            x1T[(pg * 4 + a) * 17 + jg] = pp;
        }
    }
    __syncthreads();

    if (tid < 64) {
        int p = pb + tid;
        if (p < npairs) {
            float sum = b3[0];
#pragma unroll
            for (int g = 0; g < 16; ++g) sum += x1T[tid * 17 + g];
            out[p] = sum;
        }
    }
}

// ---------------------------------------------------------------------------
// Fallback: direct per-pair kernel (only if d_ws can't hold the node tables).
// ---------------------------------------------------------------------------
__global__ __launch_bounds__(256) void mlp_kernel(
    const float* __restrict__ h,
    const int* __restrict__ pairs,
    const int* __restrict__ flag,
    const float* __restrict__ W1, const float* __restrict__ b1,
    const float* __restrict__ W2, const float* __restrict__ b2,
    const float* __restrict__ W3, const float* __restrict__ b3,
    float* __restrict__ out, int npairs)
{
    int p = blockIdx.x * 256 + threadIdx.x;
    if (p >= npairs) return;

    int s, t;
    if (*flag == 0) { s = pairs[4 * p]; t = pairs[4 * p + 2]; }
    else            { s = pairs[2 * p]; t = pairs[2 * p + 1]; }

    const float4* hs4 = (const float4*)(h + (size_t)s * EMBED);
    const float4* ht4 = (const float4*)(h + (size_t)t * EMBED);

    float acc[128];
#pragma unroll
    for (int j = 0; j < 128; ++j) acc[j] = b1[j];

#pragma unroll 1
    for (int d4 = 0; d4 < EMBED / 4; ++d4) {
        float4 a = hs4[d4];
        float4 b = ht4[d4];
        float av[4] = {a.x, a.y, a.z, a.w};
        float bv[4] = {b.x, b.y, b.z, b.w};
#pragma unroll
        for (int dd = 0; dd < 4; ++dd) {
            int k = d4 * 4 + dd;
            float f0 = av[dd], f1 = bv[dd];
            float f2 = f0 * f1;
            float f3 = fabsf(f0 - f1);
            const float* w0 = W1 + (size_t)k * 128;
            const float* w1r = w0 + 128 * 128;
            const float* w2r = w0 + 256 * 128;
            const float* w3r = w0 + 384 * 128;
#pragma unroll
            for (int j = 0; j < 128; ++j) {
                float v0 = acc[j];
                v0 = fmaf(f0, w0[j], v0);
                v0 = fmaf(f1, w1r[j], v0);
                v0 = fmaf(f2, w2r[j], v0);
                v0 = fmaf(f3, w3r[j], v0);
                acc[j] = v0;
            }
        }
    }

#pragma unroll
    for (int j = 0; j < 128; ++j) acc[j] = fmaxf(acc[j], 0.0f);

    float x2[64];
#pragma unroll
    for (int j = 0; j < 64; ++j) x2[j] = b2[j];
#pragma unroll
    for (int k = 0; k < 128; ++k) {
        float xv = acc[k];
#pragma unroll
        for (int j = 0; j < 64; ++j)
            x2[j] = fmaf(xv, W2[(size_t)k * 64 + j], x2[j]);
    }

    float lg = b3[0];
#pragma unroll
    for (int k = 0; k < 64; ++k)
        lg = fmaf(fmaxf(x2[k], 0.0f), W3[k], lg);

    out[p] = lg;
}

extern "C" void kernel_launch(void* const* d_in, const int* in_sizes, int n_in,
                              void* d_out, int out_size, void* d_ws, size_t ws_size,
                              hipStream_t stream) {
    const float* h   = (const float*)d_in[0];
    const int* pairs = (const int*)d_in[1];
    const float* W1  = (const float*)d_in[2];
    const float* b1  = (const float*)d_in[3];
    const float* W2  = (const float*)d_in[4];
    const float* b2  = (const float*)d_in[5];
    const float* W3  = (const float*)d_in[6];
    const float* b3  = (const float*)d_in[7];
    float* out = (float*)d_out;

    int npairs  = out_size;               // one logit per pair
    int n_nodes = in_sizes[0] / EMBED;

    int*   flag = (int*)d_ws;
    float* tab  = (float*)((char*)d_ws + 16);   // 16B-aligned table
    size_t need = 16 + (size_t)n_nodes * 2 * EMBED * sizeof(float);

    detect_kernel<<<1, 64, 0, stream>>>((const unsigned int*)pairs, flag);

    if (ws_size >= need) {
        node_pre_kernel<<<(n_nodes + 63) / 64, 256, 0, stream>>>(
            h, W1, b1, tab, n_nodes);
        pair_kernel_f<<<(npairs + 63) / 64, 256, 0, stream>>>(
            h, pairs, flag, tab, W1, W2, b2, W3, b3, out, npairs);
    } else {
        mlp_kernel<<<(npairs + 255) / 256, 256, 0, stream>>>(
            h, pairs, flag, W1, b1, W2, b2, W3, b3, out, npairs);
    }
}

// Round 6
// 658.622 us; speedup vs baseline: 6.0361x; 1.0670x over previous
//
#include <hip/hip_runtime.h>
#include <math.h>

#define EMBED 128
#define NPB 128   // pairs per block in pair kernel

// ---------------------------------------------------------------------------
// pairs dtype detector: reference declares int64 but harness may hand int32.
// int64 LE: odd 32-bit slots are high words of values < 100000 -> zero.
// ---------------------------------------------------------------------------
__global__ void detect_kernel(const unsigned int* __restrict__ pairs,
                              int* __restrict__ flag) {
    unsigned v = 0;
    int lane = threadIdx.x;  // 64 lanes
#pragma unroll
    for (int i = 0; i < 8; ++i) {
        v |= pairs[2 * (lane * 8 + i) + 1];
    }
    unsigned long long b = __ballot(v != 0);
    if (lane == 0) *flag = (b != 0ULL) ? 1 : 0;
}

// ---------------------------------------------------------------------------
// Node precompute (unchanged from round 5 — measured ~10 us total).
// ---------------------------------------------------------------------------
__global__ __launch_bounds__(256) void node_pre_kernel(
    const float* __restrict__ h, const float* __restrict__ W1,
    const float* __restrict__ b1, float* __restrict__ tab, int n_nodes)
{
    __shared__ float Wab[16 * 260];
    __shared__ float Fh[16 * 64];

    int tid = threadIdx.x;
    int pg  = tid & 15;
    int cg  = tid >> 4;
    int nb  = blockIdx.x * 64;

    const float4* hP = nullptr;
    if (tid < 64) {
        int n = nb + tid; if (n >= n_nodes) n = n_nodes - 1;
        hP = (const float4*)(h + (size_t)n * EMBED);
    }

    float acc[4][16];
#pragma unroll
    for (int a = 0; a < 4; ++a)
#pragma unroll
        for (int b = 0; b < 16; ++b) acc[a][b] = 0.0f;

    int wr   = tid >> 4;
    int wseg = tid & 15;

#pragma unroll 1
    for (int c = 0; c < 8; ++c) {
        {
            const float* src = (wseg < 8)
                ? (W1 + (size_t)(c * 16 + wr) * 128 + wseg * 16)
                : (W1 + (size_t)(128 + c * 16 + wr) * 128 + (wseg - 8) * 16);
            float* dst = Wab + wr * 260 + ((wseg < 8) ? wseg * 16
                                                      : 128 + (wseg - 8) * 16);
            const float4* s4 = (const float4*)src;
            float4* d4 = (float4*)dst;
#pragma unroll
            for (int q = 0; q < 4; ++q) d4[q] = s4[q];
        }
        if (tid < 64) {
#pragma unroll
            for (int q = 0; q < 4; ++q) {
                float4 v = hP[c * 4 + q];
                Fh[(q * 4 + 0) * 64 + tid] = v.x;
                Fh[(q * 4 + 1) * 64 + tid] = v.y;
                Fh[(q * 4 + 2) * 64 + tid] = v.z;
                Fh[(q * 4 + 3) * 64 + tid] = v.w;
            }
        }
        __syncthreads();
#pragma unroll 4
        for (int k = 0; k < 16; ++k) {
            float4 f = *(const float4*)(Fh + k * 64 + pg * 4);
            float fa[4] = {f.x, f.y, f.z, f.w};
            const float4* wrow = (const float4*)(Wab + k * 260 + cg * 16);
#pragma unroll
            for (int q = 0; q < 4; ++q) {
                float4 w = wrow[q];
                float wa[4] = {w.x, w.y, w.z, w.w};
#pragma unroll
                for (int a = 0; a < 4; ++a)
#pragma unroll
                    for (int b = 0; b < 4; ++b)
                        acc[a][q * 4 + b] = fmaf(fa[a], wa[b], acc[a][q * 4 + b]);
            }
        }
        __syncthreads();
    }

    float bias[16];
    if (cg < 8) {
        const float4* b4 = (const float4*)(b1 + cg * 16);
#pragma unroll
        for (int q = 0; q < 4; ++q) {
            float4 v = b4[q];
            bias[q * 4 + 0] = v.x; bias[q * 4 + 1] = v.y;
            bias[q * 4 + 2] = v.z; bias[q * 4 + 3] = v.w;
        }
    } else {
#pragma unroll
        for (int b = 0; b < 16; ++b) bias[b] = 0.0f;
    }
#pragma unroll
    for (int a = 0; a < 4; ++a) {
        int n = nb + pg * 4 + a;
        if (n < n_nodes) {
            int row = (cg < 8) ? 2 * n : 2 * n + 1;
            int col = (cg < 8) ? cg * 16 : (cg - 8) * 16;
            float4* dst = (float4*)(tab + (size_t)row * 128 + col);
#pragma unroll
            for (int q = 0; q < 4; ++q)
                dst[q] = make_float4(acc[a][q * 4 + 0] + bias[q * 4 + 0],
                                     acc[a][q * 4 + 1] + bias[q * 4 + 1],
                                     acc[a][q * 4 + 2] + bias[q * 4 + 2],
                                     acc[a][q * 4 + 3] + bias[q * 4 + 3]);
        }
    }
}

// ---------------------------------------------------------------------------
// Pair kernel v4: block = 128 pairs x 128 j, 256 threads, thread = 8p x 8j.
// Double-buffered LDS chunks with register prefetch (T14): issue chunk c+1
// global loads before computing chunk c; write to the other buffer after.
// One barrier per chunk. Layer 2 reads W2 from L1 (wave-shared addresses).
// LDS: lds[17408] floats. buf0: Wb@0 [32][132], Fb@4224 [32][136];
//      buf1: Wb@8576, Fb@12800. x1T[128][136] aliases whole region after.
// ---------------------------------------------------------------------------
__global__ __launch_bounds__(256, 2) void pair_kernel_f(
    const float* __restrict__ h,
    const int* __restrict__ pairs,
    const int* __restrict__ flag,
    const float* __restrict__ tab,
    const float* __restrict__ W1,
    const float* __restrict__ W2, const float* __restrict__ b2,
    const float* __restrict__ W3, const float* __restrict__ b3,
    float* __restrict__ out, int npairs)
{
    __shared__ float lds[17408];
    __shared__ float part[NPB * 9];
    __shared__ int sArr[NPB], tArr[NPB];

    int tid = threadIdx.x;
    int pb  = blockIdx.x * NPB;

    if (tid < NPB) {
        int p = pb + tid; if (p >= npairs) p = npairs - 1;
        int s, t;
        if (*flag == 0) { s = pairs[4 * p]; t = pairs[4 * p + 2]; }
        else            { s = pairs[2 * p]; t = pairs[2 * p + 1]; }
        sArr[tid] = s; tArr[tid] = t;
    }
    __syncthreads();

    // staging roles
    int wr   = tid >> 3;                 // 0..31 : Wb row
    int wseg = tid & 7;                  // 16-float segment
    const float* wsrc = ((wr < 16)
        ? W1 + (size_t)256 * 128 + (size_t)wr * 128
        : W1 + (size_t)384 * 128 + (size_t)(wr - 16) * 128) + wseg * 16;

    int pr = tid & 127;                  // pair for F staging
    int dh = tid >> 7;                   // dim half 0/1
    const float* hs_base = h + (size_t)sArr[pr] * EMBED + dh * 8;
    const float* ht_base = h + (size_t)tArr[pr] * EMBED + dh * 8;

    // compute roles
    int pg = tid & 15;                   // pair group of 8
    int jg = tid >> 4;                   // j group of 8

    float acc[8][8];
#pragma unroll
    for (int a = 0; a < 8; ++a)
#pragma unroll
        for (int b = 0; b < 8; ++b) acc[a][b] = 0.0f;

    // prefetch registers (named: no runtime-indexed arrays)
    float4 wp0, wp1, wp2, wp3, hp0, hp1, tp0, tp1;

#define STAGE(c) do {                                                        \
        const float4* ws_ = (const float4*)(wsrc + (size_t)(c) * 2048);      \
        wp0 = ws_[0]; wp1 = ws_[1]; wp2 = ws_[2]; wp3 = ws_[3];              \
        const float4* hp_ = (const float4*)(hs_base + (c) * 16);             \
        hp0 = hp_[0]; hp1 = hp_[1];                                          \
        const float4* tp_ = (const float4*)(ht_base + (c) * 16);             \
        tp0 = tp_[0]; tp1 = tp_[1];                                          \
    } while (0)

#define WRITELDS(wbp, fbp) do {                                              \
        float* wdst_ = (wbp) + wr * 132 + wseg * 16;                         \
        *(float4*)(wdst_ + 0)  = wp0;  *(float4*)(wdst_ + 4)  = wp1;         \
        *(float4*)(wdst_ + 8)  = wp2;  *(float4*)(wdst_ + 12) = wp3;         \
        float av_[8] = {hp0.x, hp0.y, hp0.z, hp0.w, hp1.x, hp1.y, hp1.z, hp1.w}; \
        float bv_[8] = {tp0.x, tp0.y, tp0.z, tp0.w, tp1.x, tp1.y, tp1.z, tp1.w}; \
        _Pragma("unroll")                                                    \
        for (int dd = 0; dd < 8; ++dd) {                                     \
            (fbp)[(dh * 8 + dd) * 136 + pr]      = av_[dd] * bv_[dd];        \
            (fbp)[(16 + dh * 8 + dd) * 136 + pr] = fabsf(av_[dd] - bv_[dd]); \
        }                                                                    \
    } while (0)

    STAGE(0);
    WRITELDS(lds, lds + 4224);

#pragma unroll 1
    for (int c = 0; c < 8; ++c) {
        if (c < 7) STAGE(c + 1);
        __syncthreads();
        const float* wb = (c & 1) ? (lds + 8576)  : lds;
        const float* fb = (c & 1) ? (lds + 12800) : (lds + 4224);
#pragma unroll 8
        for (int k = 0; k < 32; ++k) {
            float4 f0 = *(const float4*)(fb + k * 136 + pg * 8);
            float4 f1 = *(const float4*)(fb + k * 136 + pg * 8 + 4);
            float4 w0 = *(const float4*)(wb + k * 132 + jg * 8);
            float4 w1 = *(const float4*)(wb + k * 132 + jg * 8 + 4);
            float fa[8] = {f0.x, f0.y, f0.z, f0.w, f1.x, f1.y, f1.z, f1.w};
            float wa[8] = {w0.x, w0.y, w0.z, w0.w, w1.x, w1.y, w1.z, w1.w};
#pragma unroll
            for (int a = 0; a < 8; ++a)
#pragma unroll
                for (int b = 0; b < 8; ++b)
                    acc[a][b] = fmaf(fa[a], wa[b], acc[a][b]);
        }
        if (c < 7) {
            float* wbn = (c & 1) ? lds : (lds + 8576);
            float* fbn = (c & 1) ? (lds + 4224) : (lds + 12800);
            WRITELDS(wbn, fbn);
        }
    }

    // ---- epilogue L1: gather A[s]+B[t], relu, write x1T[j][pair] ----
    float xr[8][8];
#pragma unroll
    for (int a = 0; a < 8; ++a) {
        int s = sArr[pg * 8 + a], t = tArr[pg * 8 + a];
        const float4* A4 = (const float4*)(tab + (size_t)(2 * s) * 128 + jg * 8);
        const float4* B4 = (const float4*)(tab + (size_t)(2 * t + 1) * 128 + jg * 8);
        float4 A0 = A4[0], A1 = A4[1], B0 = B4[0], B1 = B4[1];
        xr[a][0] = fmaxf(acc[a][0] + A0.x + B0.x, 0.0f);
        xr[a][1] = fmaxf(acc[a][1] + A0.y + B0.y, 0.0f);
        xr[a][2] = fmaxf(acc[a][2] + A0.z + B0.z, 0.0f);
        xr[a][3] = fmaxf(acc[a][3] + A0.w + B0.w, 0.0f);
        xr[a][4] = fmaxf(acc[a][4] + A1.x + B1.x, 0.0f);
        xr[a][5] = fmaxf(acc[a][5] + A1.y + B1.y, 0.0f);
        xr[a][6] = fmaxf(acc[a][6] + A1.z + B1.z, 0.0f);
        xr[a][7] = fmaxf(acc[a][7] + A1.w + B1.w, 0.0f);
    }
    __syncthreads();   // all chunk-buffer reads done; x1T may overwrite region
    float* x1T = lds;  // [128 j][136]
#pragma unroll
    for (int b = 0; b < 8; ++b) {
        *(float4*)(x1T + (jg * 8 + b) * 136 + pg * 8) =
            make_float4(xr[0][b], xr[1][b], xr[2][b], xr[3][b]);
        *(float4*)(x1T + (jg * 8 + b) * 136 + pg * 8 + 4) =
            make_float4(xr[4][b], xr[5][b], xr[6][b], xr[7][b]);
    }
    __syncthreads();

    // ---- phase B: layer 2 (thread = 4 pairs x 8 i), W2 from L1 ----
    int pg2 = tid & 31;                  // pairs pg2*4 .. +3
    int ig  = tid >> 5;                  // i cols ig*8 .. +7

    float x2[4][8];
    {
        const float4* b24 = (const float4*)(b2 + ig * 8);
        float4 bb0 = b24[0], bb1 = b24[1];
#pragma unroll
        for (int a = 0; a < 4; ++a) {
            x2[a][0] = bb0.x; x2[a][1] = bb0.y; x2[a][2] = bb0.z; x2[a][3] = bb0.w;
            x2[a][4] = bb1.x; x2[a][5] = bb1.y; x2[a][6] = bb1.z; x2[a][7] = bb1.w;
        }
    }
#pragma unroll 4
    for (int k = 0; k < 128; ++k) {
        float4 xv = *(const float4*)(x1T + k * 136 + pg2 * 4);
        const float4* w24 = (const float4*)(W2 + (size_t)k * 64 + ig * 8);
        float4 w0 = w24[0], w1 = w24[1];
        float xa[4] = {xv.x, xv.y, xv.z, xv.w};
        float wa[8] = {w0.x, w0.y, w0.z, w0.w, w1.x, w1.y, w1.z, w1.w};
#pragma unroll
        for (int a = 0; a < 4; ++a)
#pragma unroll
            for (int b = 0; b < 8; ++b)
                x2[a][b] = fmaf(xa[a], wa[b], x2[a][b]);
    }

    // ---- layer 3 partials ----
    {
        const float4* w34 = (const float4*)(W3 + ig * 8);
        float4 w30 = w34[0], w31 = w34[1];
        float wa[8] = {w30.x, w30.y, w30.z, w30.w, w31.x, w31.y, w31.z, w31.w};
#pragma unroll
        for (int a = 0; a < 4; ++a) {
            float pp = 0.0f;
#pragma unroll
            for (int b = 0; b < 8; ++b)
                pp = fmaf(fmaxf(x2[a][b], 0.0f), wa[b], pp);
            part[(pg2 * 4 + a) * 9 + ig] = pp;
        }
    }
    __syncthreads();

    if (tid < NPB) {
        int p = pb + tid;
        if (p < npairs) {
            float sum = b3[0];
#pragma unroll
            for (int g = 0; g < 8; ++g) sum += part[tid * 9 + g];
            out[p] = sum;
        }
    }
#undef STAGE
#undef WRITELDS
}

// ---------------------------------------------------------------------------
// Fallback: direct per-pair kernel (only if d_ws can't hold the node tables).
// ---------------------------------------------------------------------------
__global__ __launch_bounds__(256) void mlp_kernel(
    const float* __restrict__ h,
    const int* __restrict__ pairs,
    const int* __restrict__ flag,
    const float* __restrict__ W1, const float* __restrict__ b1,
    const float* __restrict__ W2, const float* __restrict__ b2,
    const float* __restrict__ W3, const float* __restrict__ b3,
    float* __restrict__ out, int npairs)
{
    int p = blockIdx.x * 256 + threadIdx.x;
    if (p >= npairs) return;

    int s, t;
    if (*flag == 0) { s = pairs[4 * p]; t = pairs[4 * p + 2]; }
    else            { s = pairs[2 * p]; t = pairs[2 * p + 1]; }

    const float4* hs4 = (const float4*)(h + (size_t)s * EMBED);
    const float4* ht4 = (const float4*)(h + (size_t)t * EMBED);

    float acc[128];
#pragma unroll
    for (int j = 0; j < 128; ++j) acc[j] = b1[j];

#pragma unroll 1
    for (int d4 = 0; d4 < EMBED / 4; ++d4) {
        float4 a = hs4[d4];
        float4 b = ht4[d4];
        float av[4] = {a.x, a.y, a.z, a.w};
        float bv[4] = {b.x, b.y, b.z, b.w};
#pragma unroll
        for (int dd = 0; dd < 4; ++dd) {
            int k = d4 * 4 + dd;
            float f0 = av[dd], f1 = bv[dd];
            float f2 = f0 * f1;
            float f3 = fabsf(f0 - f1);
            const float* w0 = W1 + (size_t)k * 128;
            const float* w1r = w0 + 128 * 128;
            const float* w2r = w0 + 256 * 128;
            const float* w3r = w0 + 384 * 128;
#pragma unroll
            for (int j = 0; j < 128; ++j) {
                float v0 = acc[j];
                v0 = fmaf(f0, w0[j], v0);
                v0 = fmaf(f1, w1r[j], v0);
                v0 = fmaf(f2, w2r[j], v0);
                v0 = fmaf(f3, w3r[j], v0);
                acc[j] = v0;
            }
        }
    }

#pragma unroll
    for (int j = 0; j < 128; ++j) acc[j] = fmaxf(acc[j], 0.0f);

    float x2[64];
#pragma unroll
    for (int j = 0; j < 64; ++j) x2[j] = b2[j];
#pragma unroll
    for (int k = 0; k < 128; ++k) {
        float xv = acc[k];
#pragma unroll
        for (int j = 0; j < 64; ++j)
            x2[j] = fmaf(xv, W2[(size_t)k * 64 + j], x2[j]);
    }

    float lg = b3[0];
#pragma unroll
    for (int k = 0; k < 64; ++k)
        lg = fmaf(fmaxf(x2[k], 0.0f), W3[k], lg);

    out[p] = lg;
}

extern "C" void kernel_launch(void* const* d_in, const int* in_sizes, int n_in,
                              void* d_out, int out_size, void* d_ws, size_t ws_size,
                              hipStream_t stream) {
    const float* h   = (const float*)d_in[0];
    const int* pairs = (const int*)d_in[1];
    const float* W1  = (const float*)d_in[2];
    const float* b1  = (const float*)d_in[3];
    const float* W2  = (const float*)d_in[4];
    const float* b2  = (const float*)d_in[5];
    const float* W3  = (const float*)d_in[6];
    const float* b3  = (const float*)d_in[7];
    float* out = (float*)d_out;

    int npairs  = out_size;
    int n_nodes = in_sizes[0] / EMBED;

    int*   flag = (int*)d_ws;
    float* tab  = (float*)((char*)d_ws + 16);
    size_t need = 16 + (size_t)n_nodes * 2 * EMBED * sizeof(float);

    detect_kernel<<<1, 64, 0, stream>>>((const unsigned int*)pairs, flag);

    if (ws_size >= need) {
        node_pre_kernel<<<(n_nodes + 63) / 64, 256, 0, stream>>>(
            h, W1, b1, tab, n_nodes);
        pair_kernel_f<<<(npairs + NPB - 1) / NPB, 256, 0, stream>>>(
            h, pairs, flag, tab, W1, W2, b2, W3, b3, out, npairs);
    } else {
        mlp_kernel<<<(npairs + 255) / 256, 256, 0, stream>>>(
            h, pairs, flag, W1, b1, W2, b2, W3, b3, out, npairs);
    }
}

// Round 7
// 646.423 us; speedup vs baseline: 6.1500x; 1.0189x over previous
//
#include <hip/hip_runtime.h>
#include <math.h>

#define EMBED 128
#define NPB 128   // pairs per block in pair kernel

// ---------------------------------------------------------------------------
// pairs dtype detector: reference declares int64 but harness may hand int32.
// int64 LE: odd 32-bit slots are high words of values < 100000 -> zero.
// ---------------------------------------------------------------------------
__global__ void detect_kernel(const unsigned int* __restrict__ pairs,
                              int* __restrict__ flag) {
    unsigned v = 0;
    int lane = threadIdx.x;  // 64 lanes
#pragma unroll
    for (int i = 0; i < 8; ++i) {
        v |= pairs[2 * (lane * 8 + i) + 1];
    }
    unsigned long long b = __ballot(v != 0);
    if (lane == 0) *flag = (b != 0ULL) ? 1 : 0;
}

// ---------------------------------------------------------------------------
// Node precompute (unchanged — measured tiny vs pair kernel).
// ---------------------------------------------------------------------------
__global__ __launch_bounds__(256) void node_pre_kernel(
    const float* __restrict__ h, const float* __restrict__ W1,
    const float* __restrict__ b1, float* __restrict__ tab, int n_nodes)
{
    __shared__ float Wab[16 * 260];
    __shared__ float Fh[16 * 64];

    int tid = threadIdx.x;
    int pg  = tid & 15;
    int cg  = tid >> 4;
    int nb  = blockIdx.x * 64;

    const float4* hP = nullptr;
    if (tid < 64) {
        int n = nb + tid; if (n >= n_nodes) n = n_nodes - 1;
        hP = (const float4*)(h + (size_t)n * EMBED);
    }

    float acc[4][16];
#pragma unroll
    for (int a = 0; a < 4; ++a)
#pragma unroll
        for (int b = 0; b < 16; ++b) acc[a][b] = 0.0f;

    int wr   = tid >> 4;
    int wseg = tid & 15;

#pragma unroll 1
    for (int c = 0; c < 8; ++c) {
        {
            const float* src = (wseg < 8)
                ? (W1 + (size_t)(c * 16 + wr) * 128 + wseg * 16)
                : (W1 + (size_t)(128 + c * 16 + wr) * 128 + (wseg - 8) * 16);
            float* dst = Wab + wr * 260 + ((wseg < 8) ? wseg * 16
                                                      : 128 + (wseg - 8) * 16);
            const float4* s4 = (const float4*)src;
            float4* d4 = (float4*)dst;
#pragma unroll
            for (int q = 0; q < 4; ++q) d4[q] = s4[q];
        }
        if (tid < 64) {
#pragma unroll
            for (int q = 0; q < 4; ++q) {
                float4 v = hP[c * 4 + q];
                Fh[(q * 4 + 0) * 64 + tid] = v.x;
                Fh[(q * 4 + 1) * 64 + tid] = v.y;
                Fh[(q * 4 + 2) * 64 + tid] = v.z;
                Fh[(q * 4 + 3) * 64 + tid] = v.w;
            }
        }
        __syncthreads();
#pragma unroll 4
        for (int k = 0; k < 16; ++k) {
            float4 f = *(const float4*)(Fh + k * 64 + pg * 4);
            float fa[4] = {f.x, f.y, f.z, f.w};
            const float4* wrow = (const float4*)(Wab + k * 260 + cg * 16);
#pragma unroll
            for (int q = 0; q < 4; ++q) {
                float4 w = wrow[q];
                float wa[4] = {w.x, w.y, w.z, w.w};
#pragma unroll
                for (int a = 0; a < 4; ++a)
#pragma unroll
                    for (int b = 0; b < 4; ++b)
                        acc[a][q * 4 + b] = fmaf(fa[a], wa[b], acc[a][q * 4 + b]);
            }
        }
        __syncthreads();
    }

    float bias[16];
    if (cg < 8) {
        const float4* b4 = (const float4*)(b1 + cg * 16);
#pragma unroll
        for (int q = 0; q < 4; ++q) {
            float4 v = b4[q];
            bias[q * 4 + 0] = v.x; bias[q * 4 + 1] = v.y;
            bias[q * 4 + 2] = v.z; bias[q * 4 + 3] = v.w;
        }
    } else {
#pragma unroll
        for (int b = 0; b < 16; ++b) bias[b] = 0.0f;
    }
#pragma unroll
    for (int a = 0; a < 4; ++a) {
        int n = nb + pg * 4 + a;
        if (n < n_nodes) {
            int row = (cg < 8) ? 2 * n : 2 * n + 1;
            int col = (cg < 8) ? cg * 16 : (cg - 8) * 16;
            float4* dst = (float4*)(tab + (size_t)row * 128 + col);
#pragma unroll
            for (int q = 0; q < 4; ++q)
                dst[q] = make_float4(acc[a][q * 4 + 0] + bias[q * 4 + 0],
                                     acc[a][q * 4 + 1] + bias[q * 4 + 1],
                                     acc[a][q * 4 + 2] + bias[q * 4 + 2],
                                     acc[a][q * 4 + 3] + bias[q * 4 + 3]);
        }
    }
}

// ---------------------------------------------------------------------------
// Pair kernel v5: block = 128 pairs x 128 j, thread = 8p x 8j, double-buffered
// chunks with register prefetch (1 barrier/chunk).
// Round-7 changes:
//  * Fb uses in-row group-gap map o(g)=8g+4*(g>>2), row stride 140 -> the
//    hot-loop f-tile reads go 4-way -> 2-way (free).  Buffer = Wb[32][132]
//    (4224) + Fb[32][140] (4480) = 8704 floats; two buffers = 17408 = x1T.
//  * Layer 2: thread = 2 pairs x 16 i, i-block = wave id (readfirstlane) ->
//    W2/b2/W3 reads are wave-uniform -> s_load (SMEM pipe), no per-lane VMEM.
// ---------------------------------------------------------------------------
__global__ __launch_bounds__(256, 2) void pair_kernel_f(
    const float* __restrict__ h,
    const int* __restrict__ pairs,
    const int* __restrict__ flag,
    const float* __restrict__ tab,
    const float* __restrict__ W1,
    const float* __restrict__ W2, const float* __restrict__ b2,
    const float* __restrict__ W3, const float* __restrict__ b3,
    float* __restrict__ out, int npairs)
{
    __shared__ float lds[17408];
    __shared__ float part[NPB * 5];
    __shared__ int sArr[NPB], tArr[NPB];

    int tid = threadIdx.x;
    int pb  = blockIdx.x * NPB;

    if (tid < NPB) {
        int p = pb + tid; if (p >= npairs) p = npairs - 1;
        int s, t;
        if (*flag == 0) { s = pairs[4 * p]; t = pairs[4 * p + 2]; }
        else            { s = pairs[2 * p]; t = pairs[2 * p + 1]; }
        sArr[tid] = s; tArr[tid] = t;
    }
    __syncthreads();

    // staging roles
    int wr   = tid >> 3;                 // 0..31 : Wb row
    int wseg = tid & 7;                  // 16-float segment
    const float* wsrc = ((wr < 16)
        ? W1 + (size_t)256 * 128 + (size_t)wr * 128
        : W1 + (size_t)384 * 128 + (size_t)(wr - 16) * 128) + wseg * 16;

    int pr = tid & 127;                  // pair for F staging
    int dh = tid >> 7;                   // dim half 0/1
    int prm = pr + 4 * (pr >> 5);        // gap-mapped pair column
    const float* hs_base = h + (size_t)sArr[pr] * EMBED + dh * 8;
    const float* ht_base = h + (size_t)tArr[pr] * EMBED + dh * 8;

    // compute roles
    int pg = tid & 15;                   // pair group of 8
    int jg = tid >> 4;                   // j group of 8
    int po = pg * 8 + 4 * (pg >> 2);     // gap-mapped f-tile offset

    float acc[8][8];
#pragma unroll
    for (int a = 0; a < 8; ++a)
#pragma unroll
        for (int b = 0; b < 8; ++b) acc[a][b] = 0.0f;

    // prefetch registers (named: no runtime-indexed arrays)
    float4 wp0, wp1, wp2, wp3, hp0, hp1, tp0, tp1;

#define STAGE(c) do {                                                        \
        const float4* ws_ = (const float4*)(wsrc + (size_t)(c) * 2048);      \
        wp0 = ws_[0]; wp1 = ws_[1]; wp2 = ws_[2]; wp3 = ws_[3];              \
        const float4* hp_ = (const float4*)(hs_base + (c) * 16);             \
        hp0 = hp_[0]; hp1 = hp_[1];                                          \
        const float4* tp_ = (const float4*)(ht_base + (c) * 16);             \
        tp0 = tp_[0]; tp1 = tp_[1];                                          \
    } while (0)

#define WRITELDS(wbp, fbp) do {                                              \
        float* wdst_ = (wbp) + wr * 132 + wseg * 16;                         \
        *(float4*)(wdst_ + 0)  = wp0;  *(float4*)(wdst_ + 4)  = wp1;         \
        *(float4*)(wdst_ + 8)  = wp2;  *(float4*)(wdst_ + 12) = wp3;         \
        float av_[8] = {hp0.x, hp0.y, hp0.z, hp0.w, hp1.x, hp1.y, hp1.z, hp1.w}; \
        float bv_[8] = {tp0.x, tp0.y, tp0.z, tp0.w, tp1.x, tp1.y, tp1.z, tp1.w}; \
        _Pragma("unroll")                                                    \
        for (int dd = 0; dd < 8; ++dd) {                                     \
            (fbp)[(dh * 8 + dd) * 140 + prm]      = av_[dd] * bv_[dd];       \
            (fbp)[(16 + dh * 8 + dd) * 140 + prm] = fabsf(av_[dd] - bv_[dd]);\
        }                                                                    \
    } while (0)

    STAGE(0);
    WRITELDS(lds, lds + 4224);

#pragma unroll 1
    for (int c = 0; c < 8; ++c) {
        if (c < 7) STAGE(c + 1);
        __syncthreads();
        const float* wb = (c & 1) ? (lds + 8704)  : lds;
        const float* fb = (c & 1) ? (lds + 12928) : (lds + 4224);
#pragma unroll 8
        for (int k = 0; k < 32; ++k) {
            float4 f0 = *(const float4*)(fb + k * 140 + po);
            float4 f1 = *(const float4*)(fb + k * 140 + po + 4);
            float4 w0 = *(const float4*)(wb + k * 132 + jg * 8);
            float4 w1 = *(const float4*)(wb + k * 132 + jg * 8 + 4);
            float fa[8] = {f0.x, f0.y, f0.z, f0.w, f1.x, f1.y, f1.z, f1.w};
            float wa[8] = {w0.x, w0.y, w0.z, w0.w, w1.x, w1.y, w1.z, w1.w};
#pragma unroll
            for (int a = 0; a < 8; ++a)
#pragma unroll
                for (int b = 0; b < 8; ++b)
                    acc[a][b] = fmaf(fa[a], wa[b], acc[a][b]);
        }
        if (c < 7) {
            float* wbn = (c & 1) ? lds : (lds + 8704);
            float* fbn = (c & 1) ? (lds + 4224) : (lds + 12928);
            WRITELDS(wbn, fbn);
        }
    }

    // ---- epilogue L1: gather A[s]+B[t], relu, write x1T[j][pair] ----
    float xr[8][8];
#pragma unroll
    for (int a = 0; a < 8; ++a) {
        int s = sArr[pg * 8 + a], t = tArr[pg * 8 + a];
        const float4* A4 = (const float4*)(tab + (size_t)(2 * s) * 128 + jg * 8);
        const float4* B4 = (const float4*)(tab + (size_t)(2 * t + 1) * 128 + jg * 8);
        float4 A0 = A4[0], A1 = A4[1], B0 = B4[0], B1 = B4[1];
        xr[a][0] = fmaxf(acc[a][0] + A0.x + B0.x, 0.0f);
        xr[a][1] = fmaxf(acc[a][1] + A0.y + B0.y, 0.0f);
        xr[a][2] = fmaxf(acc[a][2] + A0.z + B0.z, 0.0f);
        xr[a][3] = fmaxf(acc[a][3] + A0.w + B0.w, 0.0f);
        xr[a][4] = fmaxf(acc[a][4] + A1.x + B1.x, 0.0f);
        xr[a][5] = fmaxf(acc[a][5] + A1.y + B1.y, 0.0f);
        xr[a][6] = fmaxf(acc[a][6] + A1.z + B1.z, 0.0f);
        xr[a][7] = fmaxf(acc[a][7] + A1.w + B1.w, 0.0f);
    }
    __syncthreads();   // all chunk-buffer reads done; x1T may overwrite region
    float* x1T = lds;  // [128 j][136 pair-cols]
#pragma unroll
    for (int b = 0; b < 8; ++b) {
        *(float4*)(x1T + (jg * 8 + b) * 136 + pg * 8) =
            make_float4(xr[0][b], xr[1][b], xr[2][b], xr[3][b]);
        *(float4*)(x1T + (jg * 8 + b) * 136 + pg * 8 + 4) =
            make_float4(xr[4][b], xr[5][b], xr[6][b], xr[7][b]);
    }
    __syncthreads();

    // ---- phase B: layer 2, thread = 2 pairs x 16 i, i-block = wave id ----
    // wave-uniform W2/b2/W3 addresses -> scalar (s_load) path.
    int wv  = __builtin_amdgcn_readfirstlane(tid >> 6);   // 0..3
    int pg2 = tid & 63;                                   // pairs 2pg2, 2pg2+1
    const float* W2w = W2 + wv * 16;
    const float* b2w = b2 + wv * 16;
    const float* W3w = W3 + wv * 16;

    float x2a[16], x2b[16];
#pragma unroll
    for (int i = 0; i < 16; ++i) { float bb = b2w[i]; x2a[i] = bb; x2b[i] = bb; }

#pragma unroll 2
    for (int k = 0; k < 128; ++k) {
        float2 xv = *(const float2*)(x1T + k * 136 + pg2 * 2);
        const float* wr2 = W2w + (size_t)k * 64;
#pragma unroll
        for (int i = 0; i < 16; ++i) {
            float w = wr2[i];
            x2a[i] = fmaf(xv.x, w, x2a[i]);
            x2b[i] = fmaf(xv.y, w, x2b[i]);
        }
    }

    // ---- layer 3 partials over this wave's 16 i ----
    {
        float pp0 = 0.0f, pp1 = 0.0f;
#pragma unroll
        for (int i = 0; i < 16; ++i) {
            float w = W3w[i];
            pp0 = fmaf(fmaxf(x2a[i], 0.0f), w, pp0);
            pp1 = fmaf(fmaxf(x2b[i], 0.0f), w, pp1);
        }
        part[(2 * pg2 + 0) * 5 + wv] = pp0;
        part[(2 * pg2 + 1) * 5 + wv] = pp1;
    }
    __syncthreads();

    if (tid < NPB) {
        int p = pb + tid;
        if (p < npairs) {
            out[p] = b3[0] + part[tid * 5 + 0] + part[tid * 5 + 1]
                           + part[tid * 5 + 2] + part[tid * 5 + 3];
        }
    }
#undef STAGE
#undef WRITELDS
}

// ---------------------------------------------------------------------------
// Fallback: direct per-pair kernel (only if d_ws can't hold the node tables).
// ---------------------------------------------------------------------------
__global__ __launch_bounds__(256) void mlp_kernel(
    const float* __restrict__ h,
    const int* __restrict__ pairs,
    const int* __restrict__ flag,
    const float* __restrict__ W1, const float* __restrict__ b1,
    const float* __restrict__ W2, const float* __restrict__ b2,
    const float* __restrict__ W3, const float* __restrict__ b3,
    float* __restrict__ out, int npairs)
{
    int p = blockIdx.x * 256 + threadIdx.x;
    if (p >= npairs) return;

    int s, t;
    if (*flag == 0) { s = pairs[4 * p]; t = pairs[4 * p + 2]; }
    else            { s = pairs[2 * p]; t = pairs[2 * p + 1]; }

    const float4* hs4 = (const float4*)(h + (size_t)s * EMBED);
    const float4* ht4 = (const float4*)(h + (size_t)t * EMBED);

    float acc[128];
#pragma unroll
    for (int j = 0; j < 128; ++j) acc[j] = b1[j];

#pragma unroll 1
    for (int d4 = 0; d4 < EMBED / 4; ++d4) {
        float4 a = hs4[d4];
        float4 b = ht4[d4];
        float av[4] = {a.x, a.y, a.z, a.w};
        float bv[4] = {b.x, b.y, b.z, b.w};
#pragma unroll
        for (int dd = 0; dd < 4; ++dd) {
            int k = d4 * 4 + dd;
            float f0 = av[dd], f1 = bv[dd];
            float f2 = f0 * f1;
            float f3 = fabsf(f0 - f1);
            const float* w0 = W1 + (size_t)k * 128;
            const float* w1r = w0 + 128 * 128;
            const float* w2r = w0 + 256 * 128;
            const float* w3r = w0 + 384 * 128;
#pragma unroll
            for (int j = 0; j < 128; ++j) {
                float v0 = acc[j];
                v0 = fmaf(f0, w0[j], v0);
                v0 = fmaf(f1, w1r[j], v0);
                v0 = fmaf(f2, w2r[j], v0);
                v0 = fmaf(f3, w3r[j], v0);
                acc[j] = v0;
            }
        }
    }

#pragma unroll
    for (int j = 0; j < 128; ++j) acc[j] = fmaxf(acc[j], 0.0f);

    float x2[64];
#pragma unroll
    for (int j = 0; j < 64; ++j) x2[j] = b2[j];
#pragma unroll
    for (int k = 0; k < 128; ++k) {
        float xv = acc[k];
#pragma unroll
        for (int j = 0; j < 64; ++j)
            x2[j] = fmaf(xv, W2[(size_t)k * 64 + j], x2[j]);
    }

    float lg = b3[0];
#pragma unroll
    for (int k = 0; k < 64; ++k)
        lg = fmaf(fmaxf(x2[k], 0.0f), W3[k], lg);

    out[p] = lg;
}

extern "C" void kernel_launch(void* const* d_in, const int* in_sizes, int n_in,
                              void* d_out, int out_size, void* d_ws, size_t ws_size,
                              hipStream_t stream) {
    const float* h   = (const float*)d_in[0];
    const int* pairs = (const int*)d_in[1];
    const float* W1  = (const float*)d_in[2];
    const float* b1  = (const float*)d_in[3];
    const float* W2  = (const float*)d_in[4];
    const float* b2  = (const float*)d_in[5];
    const float* W3  = (const float*)d_in[6];
    const float* b3  = (const float*)d_in[7];
    float* out = (float*)d_out;

    int npairs  = out_size;
    int n_nodes = in_sizes[0] / EMBED;

    int*   flag = (int*)d_ws;
    float* tab  = (float*)((char*)d_ws + 16);
    size_t need = 16 + (size_t)n_nodes * 2 * EMBED * sizeof(float);

    detect_kernel<<<1, 64, 0, stream>>>((const unsigned int*)pairs, flag);

    if (ws_size >= need) {
        node_pre_kernel<<<(n_nodes + 63) / 64, 256, 0, stream>>>(
            h, W1, b1, tab, n_nodes);
        pair_kernel_f<<<(npairs + NPB - 1) / NPB, 256, 0, stream>>>(
            h, pairs, flag, tab, W1, W2, b2, W3, b3, out, npairs);
    } else {
        mlp_kernel<<<(npairs + 255) / 256, 256, 0, stream>>>(
            h, pairs, flag, W1, b1, W2, b2, W3, b3, out, npairs);
    }
}

// Round 8
// 342.733 us; speedup vs baseline: 11.5995x; 1.8861x over previous
//
#include <hip/hip_runtime.h>
#include <math.h>

#define EMBED 128
#define NPB 128   // pairs per block

typedef short s16x8 __attribute__((ext_vector_type(8)));
typedef float f32x16 __attribute__((ext_vector_type(16)));
#define MF(a, b, c) __builtin_amdgcn_mfma_f32_32x32x16_bf16((a), (b), (c), 0, 0, 0)

// float -> bf16 bits, RNE
__device__ __forceinline__ unsigned short f2bf(float f) {
    unsigned u = __float_as_uint(f);
    return (unsigned short)((u + 0x7FFF + ((u >> 16) & 1)) >> 16);
}
__device__ __forceinline__ float bf2f(unsigned short h) {
    return __uint_as_float(((unsigned)h) << 16);
}

// ---------------------------------------------------------------------------
// pairs dtype detector (int64 vs int32 layout).
// ---------------------------------------------------------------------------
__global__ void detect_kernel(const unsigned int* __restrict__ pairs,
                              int* __restrict__ flag) {
    unsigned v = 0;
    int lane = threadIdx.x;
#pragma unroll
    for (int i = 0; i < 8; ++i) v |= pairs[2 * (lane * 8 + i) + 1];
    unsigned long long b = __ballot(v != 0);
    if (lane == 0) *flag = (b != 0ULL) ? 1 : 0;
}

// ---------------------------------------------------------------------------
// Setup: split W1 (512x128) and W2 (128x64) into bf16 hi/lo in FRAG-LINEAR
// layout: frag f = (jtile*K16 + kstep)*64 + lane; element e: the exact 8
// bf16 the MFMA B-operand lane needs -> wave reads are lane-consecutive 16B.
// W1F: jtile 0..3 (32 j), kstep 0..31.  W2F: ntile 0..1, kstep 0..7.
// ---------------------------------------------------------------------------
__global__ __launch_bounds__(256) void setup_w_kernel(
    const float* __restrict__ W1, const float* __restrict__ W2,
    unsigned short* __restrict__ W1Fh, unsigned short* __restrict__ W1Fl,
    unsigned short* __restrict__ W2Fh, unsigned short* __restrict__ W2Fl)
{
    int gid = blockIdx.x * 256 + threadIdx.x;
    if (gid < 8192) {                       // W1F
        int f = gid;
        int jt = f >> 11, r = f & 2047;
        int gk = r >> 6, lane = r & 63;
        int j = jt * 32 + (lane & 31);
        int kb = gk * 16 + (lane >> 5) * 8;
#pragma unroll
        for (int e = 0; e < 8; ++e) {
            float w = W1[(size_t)(kb + e) * 128 + j];
            unsigned short hb = f2bf(w);
            unsigned short lb = f2bf(w - bf2f(hb));
            W1Fh[(size_t)f * 8 + e] = hb;
            W1Fl[(size_t)f * 8 + e] = lb;
        }
    } else if (gid < 9216) {                // W2F
        int f = gid - 8192;
        int nt = f >> 9, r = f & 511;
        int gk = r >> 6, lane = r & 63;
        int i = nt * 32 + (lane & 31);
        int kb = gk * 16 + (lane >> 5) * 8;
#pragma unroll
        for (int e = 0; e < 8; ++e) {
            float w = W2[(size_t)(kb + e) * 64 + i];
            unsigned short hb = f2bf(w);
            unsigned short lb = f2bf(w - bf2f(hb));
            W2Fh[(size_t)f * 8 + e] = hb;
            W2Fl[(size_t)f * 8 + e] = lb;
        }
    }
}

// ---------------------------------------------------------------------------
// MFMA pair kernel: block = 128 pairs x 128 j, 4 waves (64p x 64j each).
// Full K=512 = [hs|ht|hs*ht|abs(hs-ht)], 4 chunks of 128k built in LDS as
// bf16 hi/lo; 3-pass split MFMA (hh+hl+lh, error ~2^-18). B-frags stream
// from frag-linear W1F/W2F (L2-hot). Layer 2 also MFMA; layer 3 shfl-reduce.
// LDS F layout: [p][136 k] ushort, granule-XOR swizzle g^=((p>>3)&7).
// ---------------------------------------------------------------------------
__global__ __launch_bounds__(256, 2) void pair_mfma_kernel(
    const float* __restrict__ h,
    const int* __restrict__ pairs,
    const int* __restrict__ flag,
    const unsigned short* __restrict__ W1Fh, const unsigned short* __restrict__ W1Fl,
    const unsigned short* __restrict__ W2Fh, const unsigned short* __restrict__ W2Fl,
    const float* __restrict__ b1, const float* __restrict__ b2,
    const float* __restrict__ W3, const float* __restrict__ b3,
    float* __restrict__ out, int npairs)
{
    __shared__ __align__(16) unsigned short fbH[128 * 136];
    __shared__ __align__(16) unsigned short fbL[128 * 136];
    __shared__ int sArr[NPB], tArr[NPB];
    __shared__ float part[NPB * 3];

    int tid  = threadIdx.x;
    int lane = tid & 63;
    int w    = tid >> 6;
    int pb   = blockIdx.x * NPB;

    if (tid < NPB) {
        int p = pb + tid; if (p >= npairs) p = npairs - 1;
        int s, t;
        if (*flag == 0) { s = pairs[4 * p]; t = pairs[4 * p + 2]; }
        else            { s = pairs[2 * p]; t = pairs[2 * p + 1]; }
        sArr[tid] = s; tArr[tid] = t;
    }
    __syncthreads();

    // ---- gather this thread's h slices (held in regs across all chunks) ----
    int pRow  = tid & 127;           // F row this thread builds
    int half  = tid >> 7;            // dim-half 0/1
    int half8 = half * 8;            // granule base
    int swzp  = (pRow >> 3) & 7;

    float hsv[64], htv[64];
    {
        const float4* hsP = (const float4*)(h + (size_t)sArr[pRow] * EMBED + half * 64);
        const float4* htP = (const float4*)(h + (size_t)tArr[pRow] * EMBED + half * 64);
#pragma unroll
        for (int i = 0; i < 16; ++i) {
            float4 a = hsP[i];
            hsv[4 * i + 0] = a.x; hsv[4 * i + 1] = a.y;
            hsv[4 * i + 2] = a.z; hsv[4 * i + 3] = a.w;
        }
#pragma unroll
        for (int i = 0; i < 16; ++i) {
            float4 b = htP[i];
            htv[4 * i + 0] = b.x; htv[4 * i + 1] = b.y;
            htv[4 * i + 2] = b.z; htv[4 * i + 3] = b.w;
        }
    }

    // ---- wave tile ----
    int prow = (w & 1) * 64;
    int jt0  = (w >> 1) * 2, jt1 = jt0 + 1;
    int jcol = (w >> 1) * 64;
    int ghalf = lane >> 5;
    int pA0 = prow + (lane & 31), pA1 = pA0 + 32;
    int oA0base = pA0 * 136, oA1base = pA1 * 136;
    int sw0 = (pA0 >> 3) & 7, sw1 = (pA1 >> 3) & 7;

    // acc init = b1 (bias folded)
    float bj0 = b1[jcol + (lane & 31)];
    float bj1 = b1[jcol + 32 + (lane & 31)];
    f32x16 acc00, acc01, acc10, acc11;
#pragma unroll
    for (int r = 0; r < 16; ++r) { acc00[r] = bj0; acc01[r] = bj1; acc10[r] = bj0; acc11[r] = bj1; }

#define BUILD(VAL) do {                                                      \
    _Pragma("unroll")                                                        \
    for (int gg = 0; gg < 8; ++gg) {                                         \
        s16x8 hv, lv;                                                        \
        _Pragma("unroll")                                                    \
        for (int e = 0; e < 8; ++e) {                                        \
            int d = gg * 8 + e;                                              \
            float v = (VAL);                                                 \
            unsigned short hb = f2bf(v);                                     \
            unsigned short lb = f2bf(v - bf2f(hb));                          \
            hv[e] = (short)hb; lv[e] = (short)lb;                            \
        }                                                                    \
        int idx = pRow * 136 + ((half8 + gg) ^ swzp) * 8;                    \
        *(s16x8*)&fbH[idx] = hv;                                             \
        *(s16x8*)&fbL[idx] = lv;                                             \
    } } while (0)

#define L1_CHUNK(c) do {                                                     \
    _Pragma("unroll")                                                        \
    for (int ks = 0; ks < 8; ++ks) {                                         \
        int g = ks * 2 + ghalf;                                              \
        int o0 = oA0base + (g ^ sw0) * 8;                                    \
        int o1 = oA1base + (g ^ sw1) * 8;                                    \
        s16x8 aH0 = *(const s16x8*)&fbH[o0];                                 \
        s16x8 aL0 = *(const s16x8*)&fbL[o0];                                 \
        s16x8 aH1 = *(const s16x8*)&fbH[o1];                                 \
        s16x8 aL1 = *(const s16x8*)&fbL[o1];                                 \
        int gk = (c) * 8 + ks;                                               \
        size_t bi0 = ((size_t)(jt0 * 32 + gk) * 64 + lane) * 8;              \
        size_t bi1 = ((size_t)(jt1 * 32 + gk) * 64 + lane) * 8;              \
        s16x8 bH0 = *(const s16x8*)&W1Fh[bi0];                               \
        s16x8 bL0 = *(const s16x8*)&W1Fl[bi0];                               \
        s16x8 bH1 = *(const s16x8*)&W1Fh[bi1];                               \
        s16x8 bL1 = *(const s16x8*)&W1Fl[bi1];                               \
        acc00 = MF(aH0, bH0, acc00); acc00 = MF(aH0, bL0, acc00); acc00 = MF(aL0, bH0, acc00); \
        acc01 = MF(aH0, bH1, acc01); acc01 = MF(aH0, bL1, acc01); acc01 = MF(aL0, bH1, acc01); \
        acc10 = MF(aH1, bH0, acc10); acc10 = MF(aH1, bL0, acc10); acc10 = MF(aL1, bH0, acc10); \
        acc11 = MF(aH1, bH1, acc11); acc11 = MF(aH1, bL1, acc11); acc11 = MF(aL1, bH1, acc11); \
    } } while (0)

    // ---- 4 K-chunks: hs | ht | hs*ht | |hs-ht| ----
    BUILD(hsv[d]);                    __syncthreads(); L1_CHUNK(0); __syncthreads();
    BUILD(htv[d]);                    __syncthreads(); L1_CHUNK(1); __syncthreads();
    BUILD(hsv[d] * htv[d]);           __syncthreads(); L1_CHUNK(2); __syncthreads();
    BUILD(fabsf(hsv[d] - htv[d]));    __syncthreads(); L1_CHUNK(3); __syncthreads();

    // ---- x1 = relu(acc): write bf16 hi/lo back to LDS in A-layout ----
#define X1WR(ACC, m, n) do {                                                 \
    int jbase = jcol + (n) * 32 + (lane & 31);                               \
    int gj = jbase >> 3, jrem = jbase & 7;                                   \
    _Pragma("unroll")                                                        \
    for (int reg = 0; reg < 16; ++reg) {                                     \
        int pr = prow + (m) * 32 + (reg & 3) + 8 * (reg >> 2) + 4 * ghalf;   \
        float x = fmaxf(ACC[reg], 0.0f);                                     \
        unsigned short hb = f2bf(x);                                         \
        unsigned short lb = f2bf(x - bf2f(hb));                              \
        int idx = pr * 136 + ((gj ^ ((pr >> 3) & 7)) * 8) + jrem;            \
        fbH[idx] = hb; fbL[idx] = lb;                                        \
    } } while (0)

    X1WR(acc00, 0, 0); X1WR(acc01, 0, 1); X1WR(acc10, 1, 0); X1WR(acc11, 1, 1);
#undef X1WR
    __syncthreads();

    // ---- layer 2 MFMA: M=128, N=64, K=128 (3-pass) ----
    int pB0 = 64 * (w & 1) + (lane & 31), pB1 = pB0 + 32;
    int oB0base = pB0 * 136, oB1base = pB1 * 136;
    int sb0 = (pB0 >> 3) & 7, sb1 = (pB1 >> 3) & 7;
    int nt = w >> 1;
    int iCol = nt * 32 + (lane & 31);

    float b2v = b2[iCol];
    f32x16 c20, c21;
#pragma unroll
    for (int r = 0; r < 16; ++r) { c20[r] = b2v; c21[r] = b2v; }

#pragma unroll
    for (int ks = 0; ks < 8; ++ks) {
        int g = ks * 2 + ghalf;
        int o0 = oB0base + (g ^ sb0) * 8;
        int o1 = oB1base + (g ^ sb1) * 8;
        s16x8 aH0 = *(const s16x8*)&fbH[o0];
        s16x8 aL0 = *(const s16x8*)&fbL[o0];
        s16x8 aH1 = *(const s16x8*)&fbH[o1];
        s16x8 aL1 = *(const s16x8*)&fbL[o1];
        size_t bi = ((size_t)(nt * 8 + ks) * 64 + lane) * 8;
        s16x8 bH = *(const s16x8*)&W2Fh[bi];
        s16x8 bL = *(const s16x8*)&W2Fl[bi];
        c20 = MF(aH0, bH, c20); c20 = MF(aH0, bL, c20); c20 = MF(aL0, bH, c20);
        c21 = MF(aH1, bH, c21); c21 = MF(aH1, bL, c21); c21 = MF(aL1, bH, c21);
    }

    // ---- layer 3: per-row dot with W3 via shfl reduce over 32 cols ----
    float w3v = W3[iCol];
#define L3RED(CC, m2) do {                                                   \
    _Pragma("unroll")                                                        \
    for (int reg = 0; reg < 16; ++reg) {                                     \
        float s = fmaxf(CC[reg], 0.0f) * w3v;                                \
        s += __shfl_xor(s, 1, 32);  s += __shfl_xor(s, 2, 32);               \
        s += __shfl_xor(s, 4, 32);  s += __shfl_xor(s, 8, 32);               \
        s += __shfl_xor(s, 16, 32);                                         \
        if ((lane & 31) == 0) {                                              \
            int pr = 64 * (w & 1) + (m2) * 32 + (reg & 3) + 8 * (reg >> 2) + 4 * ghalf; \
            part[pr * 3 + nt] = s;                                           \
        }                                                                    \
    } } while (0)

    L3RED(c20, 0); L3RED(c21, 1);
#undef L3RED
    __syncthreads();

    if (tid < NPB) {
        int p = pb + tid;
        if (p < npairs) out[p] = b3[0] + part[tid * 3 + 0] + part[tid * 3 + 1];
    }
#undef BUILD
#undef L1_CHUNK
}

// ---------------------------------------------------------------------------
// Fallback: direct per-pair fp32 kernel (only if d_ws too small).
// ---------------------------------------------------------------------------
__global__ __launch_bounds__(256) void mlp_kernel(
    const float* __restrict__ h,
    const int* __restrict__ pairs,
    const int* __restrict__ flag,
    const float* __restrict__ W1, const float* __restrict__ b1,
    const float* __restrict__ W2, const float* __restrict__ b2,
    const float* __restrict__ W3, const float* __restrict__ b3,
    float* __restrict__ out, int npairs)
{
    int p = blockIdx.x * 256 + threadIdx.x;
    if (p >= npairs) return;
    int s, t;
    if (*flag == 0) { s = pairs[4 * p]; t = pairs[4 * p + 2]; }
    else            { s = pairs[2 * p]; t = pairs[2 * p + 1]; }
    const float4* hs4 = (const float4*)(h + (size_t)s * EMBED);
    const float4* ht4 = (const float4*)(h + (size_t)t * EMBED);
    float acc[128];
#pragma unroll
    for (int j = 0; j < 128; ++j) acc[j] = b1[j];
#pragma unroll 1
    for (int d4 = 0; d4 < EMBED / 4; ++d4) {
        float4 a = hs4[d4]; float4 b = ht4[d4];
        float av[4] = {a.x, a.y, a.z, a.w};
        float bv[4] = {b.x, b.y, b.z, b.w};
#pragma unroll
        for (int dd = 0; dd < 4; ++dd) {
            int k = d4 * 4 + dd;
            float f0 = av[dd], f1 = bv[dd];
            float f2 = f0 * f1, f3 = fabsf(f0 - f1);
            const float* w0 = W1 + (size_t)k * 128;
            const float* w1r = w0 + 128 * 128;
            const float* w2r = w0 + 256 * 128;
            const float* w3r = w0 + 384 * 128;
#pragma unroll
            for (int j = 0; j < 128; ++j) {
                float v0 = acc[j];
                v0 = fmaf(f0, w0[j], v0); v0 = fmaf(f1, w1r[j], v0);
                v0 = fmaf(f2, w2r[j], v0); v0 = fmaf(f3, w3r[j], v0);
                acc[j] = v0;
            }
        }
    }
#pragma unroll
    for (int j = 0; j < 128; ++j) acc[j] = fmaxf(acc[j], 0.0f);
    float x2[64];
#pragma unroll
    for (int j = 0; j < 64; ++j) x2[j] = b2[j];
#pragma unroll
    for (int k = 0; k < 128; ++k) {
        float xv = acc[k];
#pragma unroll
        for (int j = 0; j < 64; ++j)
            x2[j] = fmaf(xv, W2[(size_t)k * 64 + j], x2[j]);
    }
    float lg = b3[0];
#pragma unroll
    for (int k = 0; k < 64; ++k)
        lg = fmaf(fmaxf(x2[k], 0.0f), W3[k], lg);
    out[p] = lg;
}

extern "C" void kernel_launch(void* const* d_in, const int* in_sizes, int n_in,
                              void* d_out, int out_size, void* d_ws, size_t ws_size,
                              hipStream_t stream) {
    const float* h   = (const float*)d_in[0];
    const int* pairs = (const int*)d_in[1];
    const float* W1  = (const float*)d_in[2];
    const float* b1  = (const float*)d_in[3];
    const float* W2  = (const float*)d_in[4];
    const float* b2  = (const float*)d_in[5];
    const float* W3  = (const float*)d_in[6];
    const float* b3  = (const float*)d_in[7];
    float* out = (float*)d_out;

    int npairs = out_size;

    int* flag = (int*)d_ws;
    unsigned short* base = (unsigned short*)((char*)d_ws + 16);
    unsigned short* W1Fh = base;                 // 65536 ushort
    unsigned short* W1Fl = base + 65536;         // 65536
    unsigned short* W2Fh = base + 131072;        // 8192
    unsigned short* W2Fl = base + 139264;        // 8192
    size_t need = 16 + (size_t)(65536 * 2 + 8192 * 2) * sizeof(unsigned short);

    detect_kernel<<<1, 64, 0, stream>>>((const unsigned int*)pairs, flag);

    if (ws_size >= need) {
        setup_w_kernel<<<36, 256, 0, stream>>>(W1, W2, W1Fh, W1Fl, W2Fh, W2Fl);
        pair_mfma_kernel<<<(npairs + NPB - 1) / NPB, 256, 0, stream>>>(
            h, pairs, flag, W1Fh, W1Fl, W2Fh, W2Fl, b1, b2, W3, b3, out, npairs);
    } else {
        mlp_kernel<<<(npairs + 255) / 256, 256, 0, stream>>>(
            h, pairs, flag, W1, b1, W2, b2, W3, b3, out, npairs);
    }
}